// Round 2
// baseline (5741.312 us; speedup 1.0000x reference)
//
#include <hip/hip_runtime.h>
#include <hip/hip_bf16.h>
#include <math.h>

// ---------------------------------------------------------------------------
// DeepSeek MLA forward, fp32 ABI (inputs/outputs are fp32 per the reference;
// comparison is done at bf16 precision with a 2% relative threshold).
// B=1, T=2048, DIM=2048, H=16, NOPE=128, ROPE=64, VD=128, QKD=192
// Q_LORA=768, KV_LORA=512, SOFTSCALE = QKD * -0.5 = -96.0 (literal mult!)
//
// Precision note: softmax logits have std ~1300 (score*-96); near-argmax
// softmax means the whole score path must stay fp32 vs the np reference.
// All intermediates are fp32 in d_ws (~87 MB).
// ---------------------------------------------------------------------------

#define T_DIM 2048
#define HEADS 16
#define D_MODEL 2048
#define NOPE_D 128
#define ROPE_D 64
#define QKD_D 192
#define VD_D 128
#define QLORA 768
#define KVLORA 512
#define KVFULL_D 576   // KV_LORA + ROPE
#define SOFTSCALE -96.0f
#define EPS_RMS 1e-6f

// ---------------------------------------------------------------------------
// C(M,N) = A(M,K,lda) @ B(N,K)^T   — 64x64 tile, 256 threads, 4x4/thread
// ---------------------------------------------------------------------------
__global__ __launch_bounds__(256) void gemm_abt(
    const float* __restrict__ A, int lda,
    const float* __restrict__ B,
    float* __restrict__ C, int M, int N, int K)
{
    __shared__ __align__(16) float As[16][68];
    __shared__ __align__(16) float Bs[16][68];
    const int tid = threadIdx.x;
    const int tx = tid & 15, ty = tid >> 4;
    const int row0 = blockIdx.y * 64, col0 = blockIdx.x * 64;
    const int lm = tid >> 2;          // 0..63
    const int lk = (tid & 3) * 4;     // 0,4,8,12

    float acc[4][4];
#pragma unroll
    for (int i = 0; i < 4; i++)
#pragma unroll
        for (int j = 0; j < 4; j++) acc[i][j] = 0.0f;

    for (int kt = 0; kt < K; kt += 16) {
        const float* ap = A + (size_t)(row0 + lm) * lda + kt + lk;
        const float* bp = B + (size_t)(col0 + lm) * K + kt + lk;
#pragma unroll
        for (int u = 0; u < 4; u++) As[lk + u][lm] = ap[u];
#pragma unroll
        for (int u = 0; u < 4; u++) Bs[lk + u][lm] = bp[u];
        __syncthreads();
#pragma unroll
        for (int kk = 0; kk < 16; kk++) {
            float4 av = *(const float4*)&As[kk][ty * 4];
            float4 bv = *(const float4*)&Bs[kk][tx * 4];
            float a[4] = {av.x, av.y, av.z, av.w};
            float b[4] = {bv.x, bv.y, bv.z, bv.w};
#pragma unroll
            for (int i = 0; i < 4; i++)
#pragma unroll
                for (int j = 0; j < 4; j++) acc[i][j] += a[i] * b[j];
        }
        __syncthreads();
    }
#pragma unroll
    for (int i = 0; i < 4; i++)
#pragma unroll
        for (int j = 0; j < 4; j++)
            C[(size_t)(row0 + ty * 4 + i) * N + col0 + tx * 4 + j] = acc[i][j];
}

// ---------------------------------------------------------------------------
// In-place RMSNorm over rows: buf[row*ld + 0..D) *= rsqrt(mean(x^2)+eps)*w
// ---------------------------------------------------------------------------
__global__ __launch_bounds__(256) void rmsnorm_inplace(
    float* __restrict__ buf, int ld, int D, const float* __restrict__ w)
{
    const int row = blockIdx.x;
    float* r = buf + (size_t)row * ld;
    float ss = 0.0f;
    for (int i = threadIdx.x; i < D; i += 256) { float v = r[i]; ss += v * v; }
#pragma unroll
    for (int o = 32; o > 0; o >>= 1) ss += __shfl_down(ss, o, 64);
    __shared__ float red[4];
    if ((threadIdx.x & 63) == 0) red[threadIdx.x >> 6] = ss;
    __syncthreads();
    ss = red[0] + red[1] + red[2] + red[3];
    const float scale = rsqrtf(ss / (float)D + EPS_RMS);
    for (int i = threadIdx.x; i < D; i += 256)
        r[i] = r[i] * scale * w[i];
}

// ---------------------------------------------------------------------------
// RoPE on q (T, H, 192) cols 128..191, in place. One thread per (t,h,i).
// ---------------------------------------------------------------------------
__global__ __launch_bounds__(256) void rope_q(
    float* __restrict__ q, const float* __restrict__ freqs)
{
    const int idx = blockIdx.x * 256 + threadIdx.x;   // T*H*32 = 1048576
    const int i = idx & 31;
    const int h = (idx >> 5) & 15;
    const int t = idx >> 9;
    const float f = freqs[t * 32 + i];
    const float c = cosf(f), s = sinf(f);
    float* p = q + ((size_t)t * HEADS + h) * QKD_D + NOPE_D + 2 * i;
    const float x1 = p[0], x2 = p[1];
    p[0] = x1 * c - x2 * s;
    p[1] = x1 * s + x2 * c;
}

// RoPE on k_pe: kvfull (T,576) cols 512..575, in place. Thread per (t,i).
__global__ __launch_bounds__(256) void rope_k(
    float* __restrict__ kvfull, const float* __restrict__ freqs)
{
    const int idx = blockIdx.x * 256 + threadIdx.x;   // T*32 = 65536
    const int i = idx & 31;
    const int t = idx >> 5;
    const float f = freqs[t * 32 + i];
    const float c = cosf(f), s = sinf(f);
    float* p = kvfull + (size_t)t * KVFULL_D + KVLORA + 2 * i;
    const float x1 = p[0], x2 = p[1];
    p[0] = x1 * c - x2 * s;
    p[1] = x1 * s + x2 * c;
}

// ---------------------------------------------------------------------------
// Causal attention, one block per (query s, head h). 256 threads.
// q: (T,H,192) roped; kv: (T,H,256) = [k_nope|v]; kpe: (T,*) stride 576
// y: (T, H*128)
// ---------------------------------------------------------------------------
__global__ __launch_bounds__(256) void attn_kernel(
    const float* __restrict__ q, const float* __restrict__ kv,
    const float* __restrict__ kpe, float* __restrict__ y)
{
    const int s = blockIdx.x, h = blockIdx.y;
    const int tid = threadIdx.x;
    __shared__ float p[T_DIM];
    __shared__ __align__(16) float qs[QKD_D];
    __shared__ float red[4];

    const float* qrow = q + ((size_t)s * HEADS + h) * QKD_D;
    for (int i = tid; i < QKD_D; i += 256) qs[i] = qrow[i];
    __syncthreads();

    const int nk = s + 1;
    float lmax = -INFINITY;
    for (int j = tid; j < nk; j += 256) {
        const float4* kn4 = (const float4*)(kv + ((size_t)j * HEADS + h) * 256);
        const float4* kp4 = (const float4*)(kpe + (size_t)j * KVFULL_D);
        float acc = 0.0f;
#pragma unroll
        for (int d = 0; d < 32; d++) {
            float4 kx = kn4[d];
            acc += qs[d * 4 + 0] * kx.x + qs[d * 4 + 1] * kx.y +
                   qs[d * 4 + 2] * kx.z + qs[d * 4 + 3] * kx.w;
        }
#pragma unroll
        for (int d = 0; d < 16; d++) {
            float4 kx = kp4[d];
            acc += qs[128 + d * 4 + 0] * kx.x + qs[128 + d * 4 + 1] * kx.y +
                   qs[128 + d * 4 + 2] * kx.z + qs[128 + d * 4 + 3] * kx.w;
        }
        acc *= SOFTSCALE;
        p[j] = acc;
        lmax = fmaxf(lmax, acc);
    }
    // block max
#pragma unroll
    for (int o = 32; o > 0; o >>= 1) lmax = fmaxf(lmax, __shfl_down(lmax, o, 64));
    if ((tid & 63) == 0) red[tid >> 6] = lmax;
    __syncthreads();
    const float gmax = fmaxf(fmaxf(red[0], red[1]), fmaxf(red[2], red[3]));
    __syncthreads();
    // exp + block sum
    float lsum = 0.0f;
    for (int j = tid; j < nk; j += 256) {
        float e = expf(p[j] - gmax);
        p[j] = e;
        lsum += e;
    }
#pragma unroll
    for (int o = 32; o > 0; o >>= 1) lsum += __shfl_down(lsum, o, 64);
    if ((tid & 63) == 0) red[tid >> 6] = lsum;
    __syncthreads();
    const float gsum = red[0] + red[1] + red[2] + red[3];
    // PV: 128 lanes, one output dim each
    if (tid < VD_D) {
        const float inv = 1.0f / gsum;
        float acc = 0.0f;
#pragma unroll 4
        for (int j = 0; j < nk; j++)
            acc += p[j] * kv[((size_t)j * HEADS + h) * 256 + 128 + tid];
        y[((size_t)s * HEADS + h) * VD_D + tid] = acc * inv;
    }
}

// ---------------------------------------------------------------------------
extern "C" void kernel_launch(void* const* d_in, const int* in_sizes, int n_in,
                              void* d_out, int out_size, void* d_ws, size_t ws_size,
                              hipStream_t stream)
{
    const float* x        = (const float*)d_in[0];
    const float* freqs    = (const float*)d_in[1];
    // d_in[2] = mask: causal tril, reproduced structurally (j <= s) — unused
    const float* wq_a     = (const float*)d_in[3];
    const float* q_norm_w = (const float*)d_in[4];
    const float* wq_b     = (const float*)d_in[5];
    const float* wkv_a    = (const float*)d_in[6];
    const float* kv_norm_w= (const float*)d_in[7];
    const float* wkv_b    = (const float*)d_in[8];
    const float* wo       = (const float*)d_in[9];
    float* out            = (float*)d_out;

    float* ws     = (float*)d_ws;
    float* qa     = ws;                              // 2048*768
    float* q      = qa + (size_t)T_DIM * QLORA;      // 2048*3072
    float* kvfull = q + (size_t)T_DIM * 3072;        // 2048*576
    float* kv     = kvfull + (size_t)T_DIM * KVFULL_D; // 2048*4096
    float* y      = kv + (size_t)T_DIM * 4096;       // 2048*2048

    dim3 blk(256);

    // q_a = x @ wq_a^T  (2048x768, K=2048)
    gemm_abt<<<dim3(QLORA/64, T_DIM/64), blk, 0, stream>>>(
        x, D_MODEL, wq_a, qa, T_DIM, QLORA, D_MODEL);
    // rms_norm rows of 768
    rmsnorm_inplace<<<T_DIM, blk, 0, stream>>>(qa, QLORA, QLORA, q_norm_w);
    // q = qa_norm @ wq_b^T  (2048x3072, K=768)
    gemm_abt<<<dim3(3072/64, T_DIM/64), blk, 0, stream>>>(
        qa, QLORA, wq_b, q, T_DIM, 3072, QLORA);
    // rope on q_pe
    rope_q<<<(T_DIM * HEADS * 32) / 256, blk, 0, stream>>>(q, freqs);
    // kv_full = x @ wkv_a^T  (2048x576, K=2048)
    gemm_abt<<<dim3(KVFULL_D/64, T_DIM/64), blk, 0, stream>>>(
        x, D_MODEL, wkv_a, kvfull, T_DIM, KVFULL_D, D_MODEL);
    // rope on k_pe (cols 512..575)
    rope_k<<<(T_DIM * 32) / 256, blk, 0, stream>>>(kvfull, freqs);
    // rms_norm on c_kv (cols 0..511, row stride 576)
    rmsnorm_inplace<<<T_DIM, blk, 0, stream>>>(kvfull, KVFULL_D, KVLORA, kv_norm_w);
    // kv = ckv_norm @ wkv_b^T  (2048x4096, K=512, lda=576)
    gemm_abt<<<dim3(4096/64, T_DIM/64), blk, 0, stream>>>(
        kvfull, KVFULL_D, wkv_b, kv, T_DIM, 4096, KVLORA);
    // attention
    attn_kernel<<<dim3(T_DIM, HEADS), blk, 0, stream>>>(q, kv, kvfull + KVLORA, y);
    // out = y @ wo^T  (2048x2048, K=2048), fp32 store
    gemm_abt<<<dim3(D_MODEL/64, T_DIM/64), blk, 0, stream>>>(
        y, D_MODEL, wo, out, T_DIM, D_MODEL, D_MODEL);
}

// Round 3
// 1506.181 us; speedup vs baseline: 3.8118x; 3.8118x over previous
//
#include <hip/hip_runtime.h>
#include <hip/hip_bf16.h>
#include <math.h>

// ---------------------------------------------------------------------------
// DeepSeek MLA forward, fp32 ABI. Round 3: flash-style tiled attention.
// B=1, T=2048, DIM=2048, H=16, NOPE=128, ROPE=64, VD=128, QKD=192
// Q_LORA=768, KV_LORA=512, SOFTSCALE = QKD * -0.5 = -96.0 (literal mult!)
//
// Precision note: softmax logits have std ~1300 (score*-96); near-argmax
// softmax means the whole score path must stay fp32 vs the np reference.
// ---------------------------------------------------------------------------

#define T_DIM 2048
#define HEADS 16
#define D_MODEL 2048
#define NOPE_D 128
#define ROPE_D 64
#define QKD_D 192
#define VD_D 128
#define QLORA 768
#define KVLORA 512
#define KVFULL_D 576   // KV_LORA + ROPE
#define SOFTSCALE -96.0f
#define EPS_RMS 1e-6f

// ---------------------------------------------------------------------------
// C(M,N) = A(M,K,lda) @ B(N,K)^T   — 64x64 tile, 256 threads, 4x4/thread
// ---------------------------------------------------------------------------
__global__ __launch_bounds__(256) void gemm_abt(
    const float* __restrict__ A, int lda,
    const float* __restrict__ B,
    float* __restrict__ C, int M, int N, int K)
{
    __shared__ __align__(16) float As[16][68];
    __shared__ __align__(16) float Bs[16][68];
    const int tid = threadIdx.x;
    const int tx = tid & 15, ty = tid >> 4;
    const int row0 = blockIdx.y * 64, col0 = blockIdx.x * 64;
    const int lm = tid >> 2;          // 0..63
    const int lk = (tid & 3) * 4;     // 0,4,8,12

    float acc[4][4];
#pragma unroll
    for (int i = 0; i < 4; i++)
#pragma unroll
        for (int j = 0; j < 4; j++) acc[i][j] = 0.0f;

    for (int kt = 0; kt < K; kt += 16) {
        const float* ap = A + (size_t)(row0 + lm) * lda + kt + lk;
        const float* bp = B + (size_t)(col0 + lm) * K + kt + lk;
#pragma unroll
        for (int u = 0; u < 4; u++) As[lk + u][lm] = ap[u];
#pragma unroll
        for (int u = 0; u < 4; u++) Bs[lk + u][lm] = bp[u];
        __syncthreads();
#pragma unroll
        for (int kk = 0; kk < 16; kk++) {
            float4 av = *(const float4*)&As[kk][ty * 4];
            float4 bv = *(const float4*)&Bs[kk][tx * 4];
            float a[4] = {av.x, av.y, av.z, av.w};
            float b[4] = {bv.x, bv.y, bv.z, bv.w};
#pragma unroll
            for (int i = 0; i < 4; i++)
#pragma unroll
                for (int j = 0; j < 4; j++) acc[i][j] += a[i] * b[j];
        }
        __syncthreads();
    }
#pragma unroll
    for (int i = 0; i < 4; i++)
#pragma unroll
        for (int j = 0; j < 4; j++)
            C[(size_t)(row0 + ty * 4 + i) * N + col0 + tx * 4 + j] = acc[i][j];
}

// ---------------------------------------------------------------------------
// In-place RMSNorm over rows: buf[row*ld + 0..D) *= rsqrt(mean(x^2)+eps)*w
// ---------------------------------------------------------------------------
__global__ __launch_bounds__(256) void rmsnorm_inplace(
    float* __restrict__ buf, int ld, int D, const float* __restrict__ w)
{
    const int row = blockIdx.x;
    float* r = buf + (size_t)row * ld;
    float ss = 0.0f;
    for (int i = threadIdx.x; i < D; i += 256) { float v = r[i]; ss += v * v; }
#pragma unroll
    for (int o = 32; o > 0; o >>= 1) ss += __shfl_down(ss, o, 64);
    __shared__ float red[4];
    if ((threadIdx.x & 63) == 0) red[threadIdx.x >> 6] = ss;
    __syncthreads();
    ss = red[0] + red[1] + red[2] + red[3];
    const float scale = rsqrtf(ss / (float)D + EPS_RMS);
    for (int i = threadIdx.x; i < D; i += 256)
        r[i] = r[i] * scale * w[i];
}

// ---------------------------------------------------------------------------
// RoPE on q (T, H, 192) cols 128..191, in place. One thread per (t,h,i).
// ---------------------------------------------------------------------------
__global__ __launch_bounds__(256) void rope_q(
    float* __restrict__ q, const float* __restrict__ freqs)
{
    const int idx = blockIdx.x * 256 + threadIdx.x;   // T*H*32 = 1048576
    const int i = idx & 31;
    const int h = (idx >> 5) & 15;
    const int t = idx >> 9;
    const float f = freqs[t * 32 + i];
    const float c = cosf(f), s = sinf(f);
    float* p = q + ((size_t)t * HEADS + h) * QKD_D + NOPE_D + 2 * i;
    const float x1 = p[0], x2 = p[1];
    p[0] = x1 * c - x2 * s;
    p[1] = x1 * s + x2 * c;
}

// RoPE on k_pe: kvfull (T,576) cols 512..575, in place. Thread per (t,i).
__global__ __launch_bounds__(256) void rope_k(
    float* __restrict__ kvfull, const float* __restrict__ freqs)
{
    const int idx = blockIdx.x * 256 + threadIdx.x;   // T*32 = 65536
    const int i = idx & 31;
    const int t = idx >> 5;
    const float f = freqs[t * 32 + i];
    const float c = cosf(f), s = sinf(f);
    float* p = kvfull + (size_t)t * KVFULL_D + KVLORA + 2 * i;
    const float x1 = p[0], x2 = p[1];
    p[0] = x1 * c - x2 * s;
    p[1] = x1 * s + x2 * c;
}

// ---------------------------------------------------------------------------
// Flash-style causal attention. One block per (head, 64-query tile).
// 256 threads as 16x16: thread (tx,ty) owns S rows ty*4..+3 / cols tx*4..+3
// and O rows ty*4..+3 / cols tx*8..+7. Online softmax state in registers
// (redundant across the 16 threads sharing a row-group).
// q: (T,H,192) roped; kv: (T,H,256) = [k_nope|v]; kpe: (T,·) stride 576
// y: (T, H*128)
// ---------------------------------------------------------------------------
__global__ __launch_bounds__(256) void attn_flash(
    const float* __restrict__ q, const float* __restrict__ kv,
    const float* __restrict__ kpe, float* __restrict__ y)
{
    // Heavy-first, balance-paired (qt, h) mapping: block b<256 gets qt 31..16,
    // block b>=256 gets qt 0..15, so co-resident pairs sum to ~32 tile-steps.
    const int bid = blockIdx.x;
    const int h = bid & 15;
    const int qt = (bid < 256) ? (31 - (bid >> 4)) : ((bid - 256) >> 4);

    const int tid = threadIdx.x;
    const int tx = tid & 15, ty = tid >> 4;

    __shared__ __align__(16) float As[16][68];   // Q sub-tile (depth x row)
    __shared__ __align__(16) float Bs[16][68];   // K sub-tile (depth x row)
    __shared__ __align__(16) float Ps[64][68];   // P tile (qrow x key)
    __shared__ __align__(16) float Vs[16][132];  // V sub-tile (key x vd)

    float O[4][8];
    float m_i[4], l_i[4];
#pragma unroll
    for (int i = 0; i < 4; i++) {
        m_i[i] = -INFINITY; l_i[i] = 0.0f;
#pragma unroll
        for (int j = 0; j < 8; j++) O[i][j] = 0.0f;
    }

    const int q_row0 = qt * 64;
    const int lm = tid >> 2;          // 0..63 (row within tile)
    const int lk4 = (tid & 3) * 4;    // 0,4,8,12 (depth offset)

    for (int kt = 0; kt <= qt; kt++) {
        const int k_row0 = kt * 64;
        float S[4][4];
#pragma unroll
        for (int i = 0; i < 4; i++)
#pragma unroll
            for (int j = 0; j < 4; j++) S[i][j] = 0.0f;

        // ---- S = Q . K^T over 192 dims, 12 chunks of 16 ----
        for (int c = 0; c < 12; c++) {
            const int kd = c * 16 + lk4;
            const float4 qv = *(const float4*)&q[((size_t)(q_row0 + lm) * HEADS + h) * QKD_D + kd];
            float4 kvv;
            if (kd < NOPE_D)
                kvv = *(const float4*)&kv[((size_t)(k_row0 + lm) * HEADS + h) * 256 + kd];
            else
                kvv = *(const float4*)&kpe[(size_t)(k_row0 + lm) * KVFULL_D + (kd - NOPE_D)];
            __syncthreads();   // prev chunk / prev k-tile consumers done
            As[lk4 + 0][lm] = qv.x; As[lk4 + 1][lm] = qv.y;
            As[lk4 + 2][lm] = qv.z; As[lk4 + 3][lm] = qv.w;
            Bs[lk4 + 0][lm] = kvv.x; Bs[lk4 + 1][lm] = kvv.y;
            Bs[lk4 + 2][lm] = kvv.z; Bs[lk4 + 3][lm] = kvv.w;
            __syncthreads();
#pragma unroll
            for (int kk = 0; kk < 16; kk++) {
                float4 av = *(const float4*)&As[kk][ty * 4];
                float4 bv = *(const float4*)&Bs[kk][tx * 4];
                float a[4] = {av.x, av.y, av.z, av.w};
                float b[4] = {bv.x, bv.y, bv.z, bv.w};
#pragma unroll
                for (int i = 0; i < 4; i++)
#pragma unroll
                    for (int j = 0; j < 4; j++) S[i][j] += a[i] * b[j];
            }
        }

        // ---- scale, causal mask, online softmax update ----
#pragma unroll
        for (int i = 0; i < 4; i++)
#pragma unroll
            for (int j = 0; j < 4; j++) S[i][j] *= SOFTSCALE;
        if (kt == qt) {
#pragma unroll
            for (int i = 0; i < 4; i++)
#pragma unroll
                for (int j = 0; j < 4; j++)
                    if (tx * 4 + j > ty * 4 + i) S[i][j] = -INFINITY;
        }
#pragma unroll
        for (int i = 0; i < 4; i++) {
            float rm = fmaxf(fmaxf(S[i][0], S[i][1]), fmaxf(S[i][2], S[i][3]));
#pragma unroll
            for (int o = 1; o < 16; o <<= 1) rm = fmaxf(rm, __shfl_xor(rm, o, 16));
            const float new_m = fmaxf(m_i[i], rm);
            const float alpha = __expf(m_i[i] - new_m);   // exp(-inf)=0 on first tile
            float rs = 0.0f;
#pragma unroll
            for (int j = 0; j < 4; j++) {
                const float p = __expf(S[i][j] - new_m);
                S[i][j] = p; rs += p;
            }
#pragma unroll
            for (int o = 1; o < 16; o <<= 1) rs += __shfl_xor(rs, o, 16);
            l_i[i] = l_i[i] * alpha + rs;
            m_i[i] = new_m;
#pragma unroll
            for (int j = 0; j < 8; j++) O[i][j] *= alpha;
            *(float4*)&Ps[ty * 4 + i][tx * 4] = *(float4*)&S[i][0];
        }

        // ---- O += P . V (64x128x64), V in 4 chunks of 16 keys ----
        for (int c = 0; c < 4; c++) {
            const int jr = c * 16 + (tid >> 4);
            const int col = (tid & 15) * 8;
            const float* vsrc = &kv[((size_t)(k_row0 + jr) * HEADS + h) * 256 + NOPE_D + col];
            const float4 v0 = *(const float4*)vsrc;
            const float4 v1 = *(const float4*)(vsrc + 4);
            __syncthreads();   // Ps written (c==0) / prev Vs consumed
            *(float4*)&Vs[tid >> 4][col] = v0;
            *(float4*)&Vs[tid >> 4][col + 4] = v1;
            __syncthreads();
#pragma unroll
            for (int jk4 = 0; jk4 < 16; jk4 += 4) {
                float pr[4][4];
#pragma unroll
                for (int i = 0; i < 4; i++)
                    *(float4*)pr[i] = *(const float4*)&Ps[ty * 4 + i][c * 16 + jk4];
#pragma unroll
                for (int u = 0; u < 4; u++) {
                    const float4 w0 = *(const float4*)&Vs[jk4 + u][tx * 8];
                    const float4 w1 = *(const float4*)&Vs[jk4 + u][tx * 8 + 4];
                    const float wv[8] = {w0.x, w0.y, w0.z, w0.w, w1.x, w1.y, w1.z, w1.w};
#pragma unroll
                    for (int i = 0; i < 4; i++)
#pragma unroll
                        for (int j = 0; j < 8; j++) O[i][j] += pr[i][u] * wv[j];
                }
            }
        }
    }

    // ---- epilogue: O /= l, store y ----
#pragma unroll
    for (int i = 0; i < 4; i++) {
        const float inv = 1.0f / l_i[i];
        const int row = q_row0 + ty * 4 + i;
        float4 o0 = {O[i][0] * inv, O[i][1] * inv, O[i][2] * inv, O[i][3] * inv};
        float4 o1 = {O[i][4] * inv, O[i][5] * inv, O[i][6] * inv, O[i][7] * inv};
        float* dst = &y[((size_t)row * HEADS + h) * VD_D + tx * 8];
        *(float4*)dst = o0;
        *(float4*)(dst + 4) = o1;
    }
}

// ---------------------------------------------------------------------------
extern "C" void kernel_launch(void* const* d_in, const int* in_sizes, int n_in,
                              void* d_out, int out_size, void* d_ws, size_t ws_size,
                              hipStream_t stream)
{
    const float* x        = (const float*)d_in[0];
    const float* freqs    = (const float*)d_in[1];
    // d_in[2] = mask: causal tril, reproduced structurally (j <= s) — unused
    const float* wq_a     = (const float*)d_in[3];
    const float* q_norm_w = (const float*)d_in[4];
    const float* wq_b     = (const float*)d_in[5];
    const float* wkv_a    = (const float*)d_in[6];
    const float* kv_norm_w= (const float*)d_in[7];
    const float* wkv_b    = (const float*)d_in[8];
    const float* wo       = (const float*)d_in[9];
    float* out            = (float*)d_out;

    float* ws     = (float*)d_ws;
    float* qa     = ws;                              // 2048*768
    float* q      = qa + (size_t)T_DIM * QLORA;      // 2048*3072
    float* kvfull = q + (size_t)T_DIM * 3072;        // 2048*576
    float* kv     = kvfull + (size_t)T_DIM * KVFULL_D; // 2048*4096
    float* y      = kv + (size_t)T_DIM * 4096;       // 2048*2048

    dim3 blk(256);

    // q_a = x @ wq_a^T  (2048x768, K=2048)
    gemm_abt<<<dim3(QLORA/64, T_DIM/64), blk, 0, stream>>>(
        x, D_MODEL, wq_a, qa, T_DIM, QLORA, D_MODEL);
    // rms_norm rows of 768
    rmsnorm_inplace<<<T_DIM, blk, 0, stream>>>(qa, QLORA, QLORA, q_norm_w);
    // q = qa_norm @ wq_b^T  (2048x3072, K=768)
    gemm_abt<<<dim3(3072/64, T_DIM/64), blk, 0, stream>>>(
        qa, QLORA, wq_b, q, T_DIM, 3072, QLORA);
    // rope on q_pe
    rope_q<<<(T_DIM * HEADS * 32) / 256, blk, 0, stream>>>(q, freqs);
    // kv_full = x @ wkv_a^T  (2048x576, K=2048)
    gemm_abt<<<dim3(KVFULL_D/64, T_DIM/64), blk, 0, stream>>>(
        x, D_MODEL, wkv_a, kvfull, T_DIM, KVFULL_D, D_MODEL);
    // rope on k_pe (cols 512..575)
    rope_k<<<(T_DIM * 32) / 256, blk, 0, stream>>>(kvfull, freqs);
    // rms_norm on c_kv (cols 0..511, row stride 576)
    rmsnorm_inplace<<<T_DIM, blk, 0, stream>>>(kvfull, KVFULL_D, KVLORA, kv_norm_w);
    // kv = ckv_norm @ wkv_b^T  (2048x4096, K=512, lda=576)
    gemm_abt<<<dim3(4096/64, T_DIM/64), blk, 0, stream>>>(
        kvfull, KVFULL_D, wkv_b, kv, T_DIM, 4096, KVLORA);
    // flash attention: 512 blocks = 16 heads x 32 q-tiles
    attn_flash<<<dim3(512), blk, 0, stream>>>(q, kv, kvfull + KVLORA, y);
    // out = y @ wo^T  (2048x2048, K=2048), fp32 store
    gemm_abt<<<dim3(D_MODEL/64, T_DIM/64), blk, 0, stream>>>(
        y, D_MODEL, wo, out, T_DIM, D_MODEL, D_MODEL);
}

// Round 4
// 1173.342 us; speedup vs baseline: 4.8931x; 1.2837x over previous
//
#include <hip/hip_runtime.h>
#include <hip/hip_bf16.h>
#include <math.h>

// ---------------------------------------------------------------------------
// DeepSeek MLA forward. Round 4: split-bf16 MFMA GEMMs (3-MFMA trick:
// A*B ~= Ahi*Bhi + Ahi*Blo + Alo*Bhi, fp32 accumulate) for the 4 large
// matmuls; fp32 VALU GEMM kept for kvfull (N=576 not /128); flash attention
// unchanged from round 3.
// Score-path accuracy: split-bf16 gives ~2^-18 relative -> logit err ~0.01
// vs softmax gaps O(100). Post-softmax path also split (uniform code).
// ---------------------------------------------------------------------------

#define T_DIM 2048
#define HEADS 16
#define D_MODEL 2048
#define NOPE_D 128
#define ROPE_D 64
#define QKD_D 192
#define VD_D 128
#define QLORA 768
#define KVLORA 512
#define KVFULL_D 576
#define SOFTSCALE -96.0f
#define EPS_RMS 1e-6f

typedef __attribute__((ext_vector_type(8))) short bf16x8;
typedef __attribute__((ext_vector_type(4))) float f32x4;

#define GLOAD_LDS16(gptr, lptr)                                               \
    __builtin_amdgcn_global_load_lds(                                         \
        (const __attribute__((address_space(1))) unsigned int*)(gptr),        \
        (__attribute__((address_space(3))) unsigned int*)(lptr), 16, 0, 0)

// ---------------------------------------------------------------------------
// Split fp32 -> (hi, lo) bf16.  n % 4 == 0; grid covers exactly n/4 lanes.
// ---------------------------------------------------------------------------
__global__ __launch_bounds__(256) void cvt_split(
    const float* __restrict__ in, __hip_bfloat16* __restrict__ hi,
    __hip_bfloat16* __restrict__ lo, int n)
{
    const int i = (blockIdx.x * 256 + threadIdx.x) * 4;
    if (i >= n) return;
    float4 v = *(const float4*)&in[i];
    float vv[4] = {v.x, v.y, v.z, v.w};
#pragma unroll
    for (int u = 0; u < 4; u++) {
        __hip_bfloat16 h = __float2bfloat16(vv[u]);
        hi[i + u] = h;
        lo[i + u] = __float2bfloat16(vv[u] - __bfloat162float(h));
    }
}

// ---------------------------------------------------------------------------
// RMSNorm row (stride ld, width D) -> packed (hi, lo) bf16 at stride D.
// ---------------------------------------------------------------------------
__global__ __launch_bounds__(256) void rmsnorm_cvt(
    const float* __restrict__ in, int ld, int D, const float* __restrict__ w,
    __hip_bfloat16* __restrict__ hi, __hip_bfloat16* __restrict__ lo)
{
    const int row = blockIdx.x;
    const float* r = in + (size_t)row * ld;
    float ss = 0.0f;
    for (int i = threadIdx.x; i < D; i += 256) { float v = r[i]; ss += v * v; }
#pragma unroll
    for (int o = 32; o > 0; o >>= 1) ss += __shfl_down(ss, o, 64);
    __shared__ float red[4];
    if ((threadIdx.x & 63) == 0) red[threadIdx.x >> 6] = ss;
    __syncthreads();
    ss = red[0] + red[1] + red[2] + red[3];
    const float scale = rsqrtf(ss / (float)D + EPS_RMS);
    for (int i = threadIdx.x; i < D; i += 256) {
        const float v = r[i] * scale * w[i];
        const __hip_bfloat16 h = __float2bfloat16(v);
        hi[(size_t)row * D + i] = h;
        lo[(size_t)row * D + i] = __float2bfloat16(v - __bfloat162float(h));
    }
}

// ---------------------------------------------------------------------------
// C(M,N) fp32 = (Ah+Al)(M,K) @ (Bh+Bl)(N,K)^T via 3 bf16 MFMAs per tile.
// 128x128 block tile, 4 waves each computing 64x64 as 4x4 MFMA 16x16x32.
// global_load_lds width-16 staging (m97 pattern). M,N %128==0, K %32==0.
// Fragment maps (HW-verified): A/B lane: [m|n = lane&15][k = quad*8+j];
// C/D lane: row = quad*4+reg, col = lane&15.
// ---------------------------------------------------------------------------
__global__ __launch_bounds__(256) void gemm_split(
    const __hip_bfloat16* __restrict__ Ah, const __hip_bfloat16* __restrict__ Al,
    const __hip_bfloat16* __restrict__ Bh, const __hip_bfloat16* __restrict__ Bl,
    float* __restrict__ C, int M, int N, int K)
{
    __shared__ __hip_bfloat16 sAh[128 * 32], sAl[128 * 32];
    __shared__ __hip_bfloat16 sBh[128 * 32], sBl[128 * 32];

    const int tid = threadIdx.x;
    const int lane = tid & 63, wave = tid >> 6;
    const int row0 = blockIdx.y * 128, col0 = blockIdx.x * 128;
    const int wm = (wave & 1) * 64, wn = (wave >> 1) * 64;
    const int fr = lane & 15, quad = lane >> 4;

    f32x4 acc[4][4];
#pragma unroll
    for (int i = 0; i < 4; i++)
#pragma unroll
        for (int j = 0; j < 4; j++) acc[i][j] = (f32x4){0.f, 0.f, 0.f, 0.f};

    // Staging geometry: thread covers tile row tid/4 (shot adds 64), 8 bf16
    // at col (tid&3)*8. LDS dest must be wave-uniform base + lane*16.
    const int trow = tid >> 2;
    const int tcol = (tid & 3) * 8;
    const size_t ldsoff = (size_t)wave * 1024;   // bytes, per shot

    for (int kt = 0; kt < K; kt += 32) {
        __syncthreads();
        {
            const __hip_bfloat16* a0 = Ah + (size_t)(row0 + trow) * K + kt + tcol;
            const __hip_bfloat16* a1 = Ah + (size_t)(row0 + 64 + trow) * K + kt + tcol;
            const __hip_bfloat16* c0 = Al + (size_t)(row0 + trow) * K + kt + tcol;
            const __hip_bfloat16* c1 = Al + (size_t)(row0 + 64 + trow) * K + kt + tcol;
            const __hip_bfloat16* b0 = Bh + (size_t)(col0 + trow) * K + kt + tcol;
            const __hip_bfloat16* b1 = Bh + (size_t)(col0 + 64 + trow) * K + kt + tcol;
            const __hip_bfloat16* d0 = Bl + (size_t)(col0 + trow) * K + kt + tcol;
            const __hip_bfloat16* d1 = Bl + (size_t)(col0 + 64 + trow) * K + kt + tcol;
            GLOAD_LDS16(a0, (char*)sAh + ldsoff);
            GLOAD_LDS16(a1, (char*)sAh + 4096 + ldsoff);
            GLOAD_LDS16(c0, (char*)sAl + ldsoff);
            GLOAD_LDS16(c1, (char*)sAl + 4096 + ldsoff);
            GLOAD_LDS16(b0, (char*)sBh + ldsoff);
            GLOAD_LDS16(b1, (char*)sBh + 4096 + ldsoff);
            GLOAD_LDS16(d0, (char*)sBl + ldsoff);
            GLOAD_LDS16(d1, (char*)sBl + 4096 + ldsoff);
        }
        __syncthreads();

        bf16x8 a_h[4], a_l[4], b_h[4], b_l[4];
#pragma unroll
        for (int mt = 0; mt < 4; mt++) {
            const int r = (wm + mt * 16 + fr) * 32 + quad * 8;
            a_h[mt] = *(const bf16x8*)&sAh[r];
            a_l[mt] = *(const bf16x8*)&sAl[r];
        }
#pragma unroll
        for (int nt = 0; nt < 4; nt++) {
            const int r = (wn + nt * 16 + fr) * 32 + quad * 8;
            b_h[nt] = *(const bf16x8*)&sBh[r];
            b_l[nt] = *(const bf16x8*)&sBl[r];
        }
#pragma unroll
        for (int mt = 0; mt < 4; mt++)
#pragma unroll
            for (int nt = 0; nt < 4; nt++) {
                acc[mt][nt] = __builtin_amdgcn_mfma_f32_16x16x32_bf16(
                    a_l[mt], b_h[nt], acc[mt][nt], 0, 0, 0);
                acc[mt][nt] = __builtin_amdgcn_mfma_f32_16x16x32_bf16(
                    a_h[mt], b_l[nt], acc[mt][nt], 0, 0, 0);
                acc[mt][nt] = __builtin_amdgcn_mfma_f32_16x16x32_bf16(
                    a_h[mt], b_h[nt], acc[mt][nt], 0, 0, 0);
            }
    }

#pragma unroll
    for (int mt = 0; mt < 4; mt++)
#pragma unroll
        for (int nt = 0; nt < 4; nt++)
#pragma unroll
            for (int r = 0; r < 4; r++)
                C[(size_t)(row0 + wm + mt * 16 + quad * 4 + r) * N +
                  col0 + wn + nt * 16 + fr] = acc[mt][nt][r];
}

// ---------------------------------------------------------------------------
// fp32 VALU GEMM (kept for kvfull, N=576): C = A(M,K,lda) @ B(N,K)^T
// ---------------------------------------------------------------------------
__global__ __launch_bounds__(256) void gemm_abt(
    const float* __restrict__ A, int lda,
    const float* __restrict__ B,
    float* __restrict__ C, int M, int N, int K)
{
    __shared__ __align__(16) float As[16][68];
    __shared__ __align__(16) float Bs[16][68];
    const int tid = threadIdx.x;
    const int tx = tid & 15, ty = tid >> 4;
    const int row0 = blockIdx.y * 64, col0 = blockIdx.x * 64;
    const int lm = tid >> 2;
    const int lk = (tid & 3) * 4;

    float acc[4][4];
#pragma unroll
    for (int i = 0; i < 4; i++)
#pragma unroll
        for (int j = 0; j < 4; j++) acc[i][j] = 0.0f;

    for (int kt = 0; kt < K; kt += 16) {
        const float* ap = A + (size_t)(row0 + lm) * lda + kt + lk;
        const float* bp = B + (size_t)(col0 + lm) * K + kt + lk;
#pragma unroll
        for (int u = 0; u < 4; u++) As[lk + u][lm] = ap[u];
#pragma unroll
        for (int u = 0; u < 4; u++) Bs[lk + u][lm] = bp[u];
        __syncthreads();
#pragma unroll
        for (int kk = 0; kk < 16; kk++) {
            float4 av = *(const float4*)&As[kk][ty * 4];
            float4 bv = *(const float4*)&Bs[kk][tx * 4];
            float a[4] = {av.x, av.y, av.z, av.w};
            float b[4] = {bv.x, bv.y, bv.z, bv.w};
#pragma unroll
            for (int i = 0; i < 4; i++)
#pragma unroll
                for (int j = 0; j < 4; j++) acc[i][j] += a[i] * b[j];
        }
        __syncthreads();
    }
#pragma unroll
    for (int i = 0; i < 4; i++)
#pragma unroll
        for (int j = 0; j < 4; j++)
            C[(size_t)(row0 + ty * 4 + i) * N + col0 + tx * 4 + j] = acc[i][j];
}

// ---------------------------------------------------------------------------
__global__ __launch_bounds__(256) void rope_q(
    float* __restrict__ q, const float* __restrict__ freqs)
{
    const int idx = blockIdx.x * 256 + threadIdx.x;
    const int i = idx & 31;
    const int h = (idx >> 5) & 15;
    const int t = idx >> 9;
    const float f = freqs[t * 32 + i];
    const float c = cosf(f), s = sinf(f);
    float* p = q + ((size_t)t * HEADS + h) * QKD_D + NOPE_D + 2 * i;
    const float x1 = p[0], x2 = p[1];
    p[0] = x1 * c - x2 * s;
    p[1] = x1 * s + x2 * c;
}

__global__ __launch_bounds__(256) void rope_k(
    float* __restrict__ kvfull, const float* __restrict__ freqs)
{
    const int idx = blockIdx.x * 256 + threadIdx.x;
    const int i = idx & 31;
    const int t = idx >> 5;
    const float f = freqs[t * 32 + i];
    const float c = cosf(f), s = sinf(f);
    float* p = kvfull + (size_t)t * KVFULL_D + KVLORA + 2 * i;
    const float x1 = p[0], x2 = p[1];
    p[0] = x1 * c - x2 * s;
    p[1] = x1 * s + x2 * c;
}

// ---------------------------------------------------------------------------
// Flash attention (round-3 kernel, unchanged).
// ---------------------------------------------------------------------------
__global__ __launch_bounds__(256) void attn_flash(
    const float* __restrict__ q, const float* __restrict__ kv,
    const float* __restrict__ kpe, float* __restrict__ y)
{
    const int bid = blockIdx.x;
    const int h = bid & 15;
    const int qt = (bid < 256) ? (31 - (bid >> 4)) : ((bid - 256) >> 4);

    const int tid = threadIdx.x;
    const int tx = tid & 15, ty = tid >> 4;

    __shared__ __align__(16) float As[16][68];
    __shared__ __align__(16) float Bs[16][68];
    __shared__ __align__(16) float Ps[64][68];
    __shared__ __align__(16) float Vs[16][132];

    float O[4][8];
    float m_i[4], l_i[4];
#pragma unroll
    for (int i = 0; i < 4; i++) {
        m_i[i] = -INFINITY; l_i[i] = 0.0f;
#pragma unroll
        for (int j = 0; j < 8; j++) O[i][j] = 0.0f;
    }

    const int q_row0 = qt * 64;
    const int lm = tid >> 2;
    const int lk4 = (tid & 3) * 4;

    for (int kt = 0; kt <= qt; kt++) {
        const int k_row0 = kt * 64;
        float S[4][4];
#pragma unroll
        for (int i = 0; i < 4; i++)
#pragma unroll
            for (int j = 0; j < 4; j++) S[i][j] = 0.0f;

        for (int c = 0; c < 12; c++) {
            const int kd = c * 16 + lk4;
            const float4 qv = *(const float4*)&q[((size_t)(q_row0 + lm) * HEADS + h) * QKD_D + kd];
            float4 kvv;
            if (kd < NOPE_D)
                kvv = *(const float4*)&kv[((size_t)(k_row0 + lm) * HEADS + h) * 256 + kd];
            else
                kvv = *(const float4*)&kpe[(size_t)(k_row0 + lm) * KVFULL_D + (kd - NOPE_D)];
            __syncthreads();
            As[lk4 + 0][lm] = qv.x; As[lk4 + 1][lm] = qv.y;
            As[lk4 + 2][lm] = qv.z; As[lk4 + 3][lm] = qv.w;
            Bs[lk4 + 0][lm] = kvv.x; Bs[lk4 + 1][lm] = kvv.y;
            Bs[lk4 + 2][lm] = kvv.z; Bs[lk4 + 3][lm] = kvv.w;
            __syncthreads();
#pragma unroll
            for (int kk = 0; kk < 16; kk++) {
                float4 av = *(const float4*)&As[kk][ty * 4];
                float4 bv = *(const float4*)&Bs[kk][tx * 4];
                float a[4] = {av.x, av.y, av.z, av.w};
                float b[4] = {bv.x, bv.y, bv.z, bv.w};
#pragma unroll
                for (int i = 0; i < 4; i++)
#pragma unroll
                    for (int j = 0; j < 4; j++) S[i][j] += a[i] * b[j];
            }
        }

#pragma unroll
        for (int i = 0; i < 4; i++)
#pragma unroll
            for (int j = 0; j < 4; j++) S[i][j] *= SOFTSCALE;
        if (kt == qt) {
#pragma unroll
            for (int i = 0; i < 4; i++)
#pragma unroll
                for (int j = 0; j < 4; j++)
                    if (tx * 4 + j > ty * 4 + i) S[i][j] = -INFINITY;
        }
#pragma unroll
        for (int i = 0; i < 4; i++) {
            float rm = fmaxf(fmaxf(S[i][0], S[i][1]), fmaxf(S[i][2], S[i][3]));
#pragma unroll
            for (int o = 1; o < 16; o <<= 1) rm = fmaxf(rm, __shfl_xor(rm, o, 16));
            const float new_m = fmaxf(m_i[i], rm);
            const float alpha = __expf(m_i[i] - new_m);
            float rs = 0.0f;
#pragma unroll
            for (int j = 0; j < 4; j++) {
                const float p = __expf(S[i][j] - new_m);
                S[i][j] = p; rs += p;
            }
#pragma unroll
            for (int o = 1; o < 16; o <<= 1) rs += __shfl_xor(rs, o, 16);
            l_i[i] = l_i[i] * alpha + rs;
            m_i[i] = new_m;
#pragma unroll
            for (int j = 0; j < 8; j++) O[i][j] *= alpha;
            *(float4*)&Ps[ty * 4 + i][tx * 4] = *(float4*)&S[i][0];
        }

        for (int c = 0; c < 4; c++) {
            const int jr = c * 16 + (tid >> 4);
            const int col = (tid & 15) * 8;
            const float* vsrc = &kv[((size_t)(k_row0 + jr) * HEADS + h) * 256 + NOPE_D + col];
            const float4 v0 = *(const float4*)vsrc;
            const float4 v1 = *(const float4*)(vsrc + 4);
            __syncthreads();
            *(float4*)&Vs[tid >> 4][col] = v0;
            *(float4*)&Vs[tid >> 4][col + 4] = v1;
            __syncthreads();
#pragma unroll
            for (int jk4 = 0; jk4 < 16; jk4 += 4) {
                float pr[4][4];
#pragma unroll
                for (int i = 0; i < 4; i++)
                    *(float4*)pr[i] = *(const float4*)&Ps[ty * 4 + i][c * 16 + jk4];
#pragma unroll
                for (int u = 0; u < 4; u++) {
                    const float4 w0 = *(const float4*)&Vs[jk4 + u][tx * 8];
                    const float4 w1 = *(const float4*)&Vs[jk4 + u][tx * 8 + 4];
                    const float wv[8] = {w0.x, w0.y, w0.z, w0.w, w1.x, w1.y, w1.z, w1.w};
#pragma unroll
                    for (int i = 0; i < 4; i++)
#pragma unroll
                        for (int j = 0; j < 8; j++) O[i][j] += pr[i][u] * wv[j];
                }
            }
        }
    }

#pragma unroll
    for (int i = 0; i < 4; i++) {
        const float inv = 1.0f / l_i[i];
        const int row = q_row0 + ty * 4 + i;
        float4 o0 = {O[i][0] * inv, O[i][1] * inv, O[i][2] * inv, O[i][3] * inv};
        float4 o1 = {O[i][4] * inv, O[i][5] * inv, O[i][6] * inv, O[i][7] * inv};
        float* dst = &y[((size_t)row * HEADS + h) * VD_D + tx * 8];
        *(float4*)dst = o0;
        *(float4*)(dst + 4) = o1;
    }
}

// ---------------------------------------------------------------------------
// Workspace layout (time-multiplexed, peak 82.5 MB -- round-2's 86.6 MB fit):
//  R1 @0        (16.78MB): xh,xl  -> ckvh,ckvl,wvh,wvl -> y fp32
//  R2 @16.78MB  ( 6.29MB): wah,wal -> qah,qal
//  R3 @23.07MB  (25.17MB): q fp32
//  R4 @48.23MB  ( 4.72MB): kvfull fp32
//  R5 @52.95MB  (33.55MB): wbh,wbl,qa fp32 -> kv fp32 -> yh,yl,woh,wol
// ---------------------------------------------------------------------------
extern "C" void kernel_launch(void* const* d_in, const int* in_sizes, int n_in,
                              void* d_out, int out_size, void* d_ws, size_t ws_size,
                              hipStream_t stream)
{
    const float* x        = (const float*)d_in[0];
    const float* freqs    = (const float*)d_in[1];
    const float* wq_a     = (const float*)d_in[3];
    const float* q_norm_w = (const float*)d_in[4];
    const float* wq_b     = (const float*)d_in[5];
    const float* wkv_a    = (const float*)d_in[6];
    const float* kv_norm_w= (const float*)d_in[7];
    const float* wkv_b    = (const float*)d_in[8];
    const float* wo       = (const float*)d_in[9];
    float* out            = (float*)d_out;

    char* ws = (char*)d_ws;
    typedef __hip_bfloat16 bf;
    // R1
    bf* xh   = (bf*)(ws);                        // 8,388,608 B
    bf* xl   = (bf*)(ws + 8388608);
    bf* ckvh = (bf*)(ws);                        // 2,097,152 B
    bf* ckvl = (bf*)(ws + 2097152);
    bf* wvh  = (bf*)(ws + 4194304);              // 4,194,304 B
    bf* wvl  = (bf*)(ws + 8388608);
    float* y = (float*)(ws);                     // 16,777,216 B
    // R2
    bf* wah  = (bf*)(ws + 16777216);             // 3,145,728 B
    bf* wal  = (bf*)(ws + 19922944);
    bf* qah  = (bf*)(ws + 16777216);
    bf* qal  = (bf*)(ws + 19922944);
    // R3
    float* q = (float*)(ws + 23068672);          // 25,165,824 B
    // R4
    float* kvfull = (float*)(ws + 48234496);     // 4,718,592 B
    // R5
    bf* wbh  = (bf*)(ws + 52953088);             // 4,718,592 B
    bf* wbl  = (bf*)(ws + 57671680);
    float* qa = (float*)(ws + 62390272);         // 6,291,456 B
    float* kv = (float*)(ws + 52953088);         // 33,554,432 B
    bf* yh   = (bf*)(ws + 52953088);             // 8,388,608 B
    bf* yl   = (bf*)(ws + 61341696);
    bf* woh  = (bf*)(ws + 69730304);
    bf* wol  = (bf*)(ws + 78118912);

    dim3 blk(256);

    // 1) splits for GEMM1
    cvt_split<<<(D_MODEL * D_MODEL) / 1024, blk, 0, stream>>>(x, xh, xl, D_MODEL * D_MODEL);
    cvt_split<<<(QLORA * D_MODEL) / 1024, blk, 0, stream>>>(wq_a, wah, wal, QLORA * D_MODEL);
    // 2) qa = x @ wq_a^T  (2048x768, K=2048)
    gemm_split<<<dim3(QLORA / 128, T_DIM / 128), blk, 0, stream>>>(
        xh, xl, wah, wal, qa, T_DIM, QLORA, D_MODEL);
    // 3) rmsnorm + split
    rmsnorm_cvt<<<T_DIM, blk, 0, stream>>>(qa, QLORA, QLORA, q_norm_w, qah, qal);
    // 4) q = qa_norm @ wq_b^T  (2048x3072, K=768)
    cvt_split<<<(3072 * QLORA) / 1024, blk, 0, stream>>>(wq_b, wbh, wbl, 3072 * QLORA);
    gemm_split<<<dim3(3072 / 128, T_DIM / 128), blk, 0, stream>>>(
        qah, qal, wbh, wbl, q, T_DIM, 3072, QLORA);
    rope_q<<<(T_DIM * HEADS * 32) / 256, blk, 0, stream>>>(q, freqs);
    // 5) kvfull = x @ wkv_a^T  (2048x576, K=2048) -- fp32 VALU (N not /128)
    gemm_abt<<<dim3(KVFULL_D / 64, T_DIM / 64), blk, 0, stream>>>(
        x, D_MODEL, wkv_a, kvfull, T_DIM, KVFULL_D, D_MODEL);
    rope_k<<<(T_DIM * 32) / 256, blk, 0, stream>>>(kvfull, freqs);
    // 6) rmsnorm c_kv + split
    rmsnorm_cvt<<<T_DIM, blk, 0, stream>>>(kvfull, KVFULL_D, KVLORA, kv_norm_w, ckvh, ckvl);
    // 7) kv = ckv_norm @ wkv_b^T  (2048x4096, K=512)
    cvt_split<<<(4096 * KVLORA) / 1024, blk, 0, stream>>>(wkv_b, wvh, wvl, 4096 * KVLORA);
    gemm_split<<<dim3(4096 / 128, T_DIM / 128), blk, 0, stream>>>(
        ckvh, ckvl, wvh, wvl, kv, T_DIM, 4096, KVLORA);
    // 8) flash attention -> y
    attn_flash<<<dim3(512), blk, 0, stream>>>(q, kv, kvfull + KVLORA, y);
    // 9) out = y @ wo^T  (2048x2048, K=2048)
    cvt_split<<<(D_MODEL * D_MODEL) / 1024, blk, 0, stream>>>(y, yh, yl, D_MODEL * D_MODEL);
    cvt_split<<<(D_MODEL * D_MODEL) / 1024, blk, 0, stream>>>(wo, woh, wol, D_MODEL * D_MODEL);
    gemm_split<<<dim3(D_MODEL / 128, T_DIM / 128), blk, 0, stream>>>(
        yh, yl, woh, wol, out, T_DIM, D_MODEL, D_MODEL);
}

// Round 5
// 720.037 us; speedup vs baseline: 7.9736x; 1.6296x over previous
//
#include <hip/hip_runtime.h>
#include <hip/hip_bf16.h>
#include <math.h>

// ---------------------------------------------------------------------------
// DeepSeek MLA forward. Round 5: full MFMA pipeline.
//  - All 5 GEMMs: split-bf16 3-MFMA (A*B ~= Ah*Bh + Ah*Bl + Al*Bh), fp32 acc.
//  - Attention: flash-style MFMA; S path split-bf16 (fp32-equivalent), softmax
//    fp32 in registers, P/V single bf16 MFMA (post-softmax, 0.2% random err).
//  - Fused epilogues: q-GEMM does RoPE + split write; kv-GEMM writes
//    kn(hi,lo)/v(hi); attention writes y split.
//  Workspace: time-multiplexed arena, peak 84.4 MB (86.5 MB proven fit).
// ---------------------------------------------------------------------------

#define T_DIM 2048
#define HEADS 16
#define D_MODEL 2048
#define NOPE_D 128
#define ROPE_D 64
#define QKD_D 192
#define VD_D 128
#define QLORA 768
#define KVLORA 512
#define KVFULL_D 576
#define SOFTSCALE -96.0f
#define EPS_RMS 1e-6f

typedef __hip_bfloat16 bf;
typedef __attribute__((ext_vector_type(8))) short bf16x8;
typedef __attribute__((ext_vector_type(4))) float f32x4;

#define GLOAD_LDS16(gptr, lptr)                                               \
    __builtin_amdgcn_global_load_lds(                                         \
        (const __attribute__((address_space(1))) unsigned int*)(gptr),        \
        (__attribute__((address_space(3))) unsigned int*)(lptr), 16, 0, 0)

__device__ __forceinline__ void split2(float v, bf* hi, bf* lo) {
    bf h = __float2bfloat16(v);
    *hi = h;
    *lo = __float2bfloat16(v - __bfloat162float(h));
}

// ---------------------------------------------------------------------------
// fp32 -> (hi,lo) bf16, n % 1024 == 0
// ---------------------------------------------------------------------------
__global__ __launch_bounds__(256) void cvt_split(
    const float* __restrict__ in, bf* __restrict__ hi, bf* __restrict__ lo, int n)
{
    const int i = (blockIdx.x * 256 + threadIdx.x) * 4;
    if (i >= n) return;
    float4 v = *(const float4*)&in[i];
    float vv[4] = {v.x, v.y, v.z, v.w};
#pragma unroll
    for (int u = 0; u < 4; u++) split2(vv[u], &hi[i + u], &lo[i + u]);
}

// ---------------------------------------------------------------------------
// RMSNorm row (stride ld, width D) -> packed (hi,lo) bf16 at stride D.
// ---------------------------------------------------------------------------
__global__ __launch_bounds__(256) void rmsnorm_cvt(
    const float* __restrict__ in, int ld, int D, const float* __restrict__ w,
    bf* __restrict__ hi, bf* __restrict__ lo)
{
    const int row = blockIdx.x;
    const float* r = in + (size_t)row * ld;
    float ss = 0.0f;
    for (int i = threadIdx.x; i < D; i += 256) { float v = r[i]; ss += v * v; }
#pragma unroll
    for (int o = 32; o > 0; o >>= 1) ss += __shfl_down(ss, o, 64);
    __shared__ float red[4];
    if ((threadIdx.x & 63) == 0) red[threadIdx.x >> 6] = ss;
    __syncthreads();
    ss = red[0] + red[1] + red[2] + red[3];
    const float scale = rsqrtf(ss / (float)D + EPS_RMS);
    for (int i = threadIdx.x; i < D; i += 256) {
        const float v = r[i] * scale * w[i];
        split2(v, &hi[(size_t)row * D + i], &lo[(size_t)row * D + i]);
    }
}

// ---------------------------------------------------------------------------
// RoPE k_pe: kvfull fp32 cols 512..575 -> kpeh/kpel (T,64). Thread per (t,i).
// ---------------------------------------------------------------------------
__global__ __launch_bounds__(256) void rope_k_cvt(
    const float* __restrict__ kvfull, const float* __restrict__ freqs,
    bf* __restrict__ kpeh, bf* __restrict__ kpel)
{
    const int idx = blockIdx.x * 256 + threadIdx.x;   // 65536
    const int i = idx & 31, t = idx >> 5;
    const float f = freqs[t * 32 + i];
    float sn, cs; sincosf(f, &sn, &cs);
    const float x1 = kvfull[(size_t)t * KVFULL_D + KVLORA + 2 * i];
    const float x2 = kvfull[(size_t)t * KVFULL_D + KVLORA + 2 * i + 1];
    split2(x1 * cs - x2 * sn, &kpeh[t * 64 + 2 * i], &kpel[t * 64 + 2 * i]);
    split2(x1 * sn + x2 * cs, &kpeh[t * 64 + 2 * i + 1], &kpel[t * 64 + 2 * i + 1]);
}

// ---------------------------------------------------------------------------
// vh (T,H,128) -> vT (H,128,T), 32x32 LDS tiles.
// ---------------------------------------------------------------------------
__global__ __launch_bounds__(256) void transpose_v(
    const bf* __restrict__ vh, bf* __restrict__ vT)
{
    __shared__ bf s[32][33];
    const int t0 = blockIdx.x * 32, d0 = blockIdx.y * 32, h = blockIdx.z;
    const int tid = threadIdx.x;
    const int i = tid >> 3, j0 = (tid & 7) * 4;
    const bf* src = vh + ((size_t)(t0 + i) * 16 + h) * 128 + d0 + j0;
#pragma unroll
    for (int u = 0; u < 4; u++) s[i][j0 + u] = src[u];
    __syncthreads();
    const int jj = tid >> 3, i0 = (tid & 7) * 4;
    bf* dst = vT + ((size_t)h * 128 + d0 + jj) * 2048 + t0 + i0;
#pragma unroll
    for (int u = 0; u < 4; u++) dst[u] = s[i0 + u][jj];
}

// ---------------------------------------------------------------------------
// Split-bf16 GEMM, 128x128 tile, 4 waves, 16x16x32 MFMA, m97 staging.
// MODE 0: C fp32 (+N guard).  MODE 1: RoPE on d>=128 + split -> Oh/Ol (q).
// MODE 2: col=h*256+d: d<128 -> split Oh/Ol (kn); d>=128 -> O2 hi (v).
// ---------------------------------------------------------------------------
template <int MODE>
__global__ __launch_bounds__(256) void gemm_split(
    const bf* __restrict__ Ah, const bf* __restrict__ Al,
    const bf* __restrict__ Bh, const bf* __restrict__ Bl,
    const float* __restrict__ freqs,
    float* __restrict__ Cf, bf* __restrict__ Oh, bf* __restrict__ Ol,
    bf* __restrict__ O2, int M, int N, int K)
{
    __shared__ bf sAh[128 * 32], sAl[128 * 32];
    __shared__ bf sBh[128 * 32], sBl[128 * 32];

    const int tid = threadIdx.x;
    const int lane = tid & 63, wave = tid >> 6;
    const int row0 = blockIdx.y * 128, col0 = blockIdx.x * 128;
    const int wm = (wave & 1) * 64, wn = (wave >> 1) * 64;
    const int fr = lane & 15, quad = lane >> 4;

    f32x4 acc[4][4];
#pragma unroll
    for (int i = 0; i < 4; i++)
#pragma unroll
        for (int j = 0; j < 4; j++) acc[i][j] = (f32x4){0.f, 0.f, 0.f, 0.f};

    const int trow = tid >> 2;
    const int tcol = (tid & 3) * 8;
    const size_t ldsoff = (size_t)wave * 1024;
    int br0 = col0 + trow;      if (br0 > N - 1) br0 = N - 1;
    int br1 = col0 + 64 + trow; if (br1 > N - 1) br1 = N - 1;

    for (int kt = 0; kt < K; kt += 32) {
        __syncthreads();
        GLOAD_LDS16(Ah + (size_t)(row0 + trow) * K + kt + tcol,      (char*)sAh + ldsoff);
        GLOAD_LDS16(Ah + (size_t)(row0 + 64 + trow) * K + kt + tcol, (char*)sAh + 4096 + ldsoff);
        GLOAD_LDS16(Al + (size_t)(row0 + trow) * K + kt + tcol,      (char*)sAl + ldsoff);
        GLOAD_LDS16(Al + (size_t)(row0 + 64 + trow) * K + kt + tcol, (char*)sAl + 4096 + ldsoff);
        GLOAD_LDS16(Bh + (size_t)br0 * K + kt + tcol, (char*)sBh + ldsoff);
        GLOAD_LDS16(Bh + (size_t)br1 * K + kt + tcol, (char*)sBh + 4096 + ldsoff);
        GLOAD_LDS16(Bl + (size_t)br0 * K + kt + tcol, (char*)sBl + ldsoff);
        GLOAD_LDS16(Bl + (size_t)br1 * K + kt + tcol, (char*)sBl + 4096 + ldsoff);
        __syncthreads();

        bf16x8 a_h[4], a_l[4], b_h[4], b_l[4];
#pragma unroll
        for (int mt = 0; mt < 4; mt++) {
            const int r = (wm + mt * 16 + fr) * 32 + quad * 8;
            a_h[mt] = *(const bf16x8*)&sAh[r];
            a_l[mt] = *(const bf16x8*)&sAl[r];
        }
#pragma unroll
        for (int nt = 0; nt < 4; nt++) {
            const int r = (wn + nt * 16 + fr) * 32 + quad * 8;
            b_h[nt] = *(const bf16x8*)&sBh[r];
            b_l[nt] = *(const bf16x8*)&sBl[r];
        }
#pragma unroll
        for (int mt = 0; mt < 4; mt++)
#pragma unroll
            for (int nt = 0; nt < 4; nt++) {
                acc[mt][nt] = __builtin_amdgcn_mfma_f32_16x16x32_bf16(
                    a_l[mt], b_h[nt], acc[mt][nt], 0, 0, 0);
                acc[mt][nt] = __builtin_amdgcn_mfma_f32_16x16x32_bf16(
                    a_h[mt], b_l[nt], acc[mt][nt], 0, 0, 0);
                acc[mt][nt] = __builtin_amdgcn_mfma_f32_16x16x32_bf16(
                    a_h[mt], b_h[nt], acc[mt][nt], 0, 0, 0);
            }
    }

#pragma unroll
    for (int mt = 0; mt < 4; mt++)
#pragma unroll
        for (int nt = 0; nt < 4; nt++) {
            const int colb = col0 + wn + nt * 16;
            const int col = colb + fr;
            if (MODE == 0) {
#pragma unroll
                for (int r = 0; r < 4; r++) {
                    const int row = row0 + wm + mt * 16 + quad * 4 + r;
                    if (col < N) Cf[(size_t)row * N + col] = acc[mt][nt][r];
                }
            } else if (MODE == 1) {
                const int d0 = colb % 192;          // uniform per nt
                const bool rope = (d0 >= 128);
                const int ii = (d0 + fr - 128) >> 1;
#pragma unroll
                for (int r = 0; r < 4; r++) {
                    const int row = row0 + wm + mt * 16 + quad * 4 + r;
                    float v = acc[mt][nt][r];
                    if (rope) {
                        const float other = __shfl_xor(v, 1);
                        float sn, cs; sincosf(freqs[row * 32 + ii], &sn, &cs);
                        v = (fr & 1) ? (other * sn + v * cs) : (v * cs - other * sn);
                    }
                    bf h8, l8; split2(v, &h8, &l8);
                    Oh[(size_t)row * N + col] = h8;
                    Ol[(size_t)row * N + col] = l8;
                }
            } else {
                const int hh = col >> 8;
                const int d = col & 255;            // d<128 uniform per nt
#pragma unroll
                for (int r = 0; r < 4; r++) {
                    const int row = row0 + wm + mt * 16 + quad * 4 + r;
                    const float v = acc[mt][nt][r];
                    if (d < 128) {
                        bf h8, l8; split2(v, &h8, &l8);
                        Oh[(size_t)row * 2048 + hh * 128 + d] = h8;
                        Ol[(size_t)row * 2048 + hh * 128 + d] = l8;
                    } else {
                        O2[(size_t)row * 2048 + hh * 128 + (d - 128)] = __float2bfloat16(v);
                    }
                }
            }
        }
}

// ---------------------------------------------------------------------------
// MFMA flash attention. Block = (head, 64-q-tile), 512 blocks, 4 waves.
// S: 64q x 128k, split-bf16 3-MFMA over 192 dims (6 chunks of 32).
// Online softmax fp32 in C-frags; P bf16 -> LDS; PV single bf16 MFMA with
// vT (H,128,T). Epilogue writes y split (hi,lo).
// ---------------------------------------------------------------------------
__global__ __launch_bounds__(256, 2) void attn_mfma(
    const bf* __restrict__ qh, const bf* __restrict__ ql,
    const bf* __restrict__ knh, const bf* __restrict__ knl,
    const bf* __restrict__ kpeh, const bf* __restrict__ kpel,
    const bf* __restrict__ vT,
    bf* __restrict__ yh, bf* __restrict__ yl)
{
    const int bid = blockIdx.x;
    const int h = bid & 15;
    const int qt = (bid < 256) ? (31 - (bid >> 4)) : ((bid - 256) >> 4);
    const int tid = threadIdx.x;
    const int lane = tid & 63, wave = tid >> 6;
    const int fr = lane & 15, quad = lane >> 4;
    const int wn = wave * 32;

    __shared__ bf sQh[64 * 32], sQl[64 * 32];
    __shared__ bf sKh[128 * 32], sKl[128 * 32];
    __shared__ bf Ps[64 * 128];
    __shared__ bf sVt[128 * 32];
    __shared__ float redM[64][4];
    __shared__ float redS[64][4];

    float m_i[16], l_i[16];
    f32x4 O[4][2];
#pragma unroll
    for (int i = 0; i < 16; i++) { m_i[i] = -INFINITY; l_i[i] = 0.0f; }
#pragma unroll
    for (int mt = 0; mt < 4; mt++)
#pragma unroll
        for (int nt = 0; nt < 2; nt++) O[mt][nt] = (f32x4){0.f, 0.f, 0.f, 0.f};

    const int q0 = qt * 64;
    const int nkt = (64 * qt + 191) >> 7;
    const int trow = tid >> 2, tcol = (tid & 3) * 8;
    const size_t loff = (size_t)wave * 1024;

    for (int kt = 0; kt < nkt; kt++) {
        const int k0 = kt * 128;
        f32x4 S[4][2];
#pragma unroll
        for (int mt = 0; mt < 4; mt++)
#pragma unroll
            for (int nt = 0; nt < 2; nt++) S[mt][nt] = (f32x4){0.f, 0.f, 0.f, 0.f};

        for (int ch = 0; ch < 6; ch++) {
            const int d0 = ch * 32;
            __syncthreads();
            GLOAD_LDS16(qh + ((size_t)(q0 + trow) * 16 + h) * 192 + d0 + tcol, (char*)sQh + loff);
            GLOAD_LDS16(ql + ((size_t)(q0 + trow) * 16 + h) * 192 + d0 + tcol, (char*)sQl + loff);
            if (d0 < 128) {
                GLOAD_LDS16(knh + ((size_t)(k0 + trow) * 16 + h) * 128 + d0 + tcol,      (char*)sKh + loff);
                GLOAD_LDS16(knh + ((size_t)(k0 + 64 + trow) * 16 + h) * 128 + d0 + tcol, (char*)sKh + 4096 + loff);
                GLOAD_LDS16(knl + ((size_t)(k0 + trow) * 16 + h) * 128 + d0 + tcol,      (char*)sKl + loff);
                GLOAD_LDS16(knl + ((size_t)(k0 + 64 + trow) * 16 + h) * 128 + d0 + tcol, (char*)sKl + 4096 + loff);
            } else {
                GLOAD_LDS16(kpeh + (size_t)(k0 + trow) * 64 + (d0 - 128) + tcol,      (char*)sKh + loff);
                GLOAD_LDS16(kpeh + (size_t)(k0 + 64 + trow) * 64 + (d0 - 128) + tcol, (char*)sKh + 4096 + loff);
                GLOAD_LDS16(kpel + (size_t)(k0 + trow) * 64 + (d0 - 128) + tcol,      (char*)sKl + loff);
                GLOAD_LDS16(kpel + (size_t)(k0 + 64 + trow) * 64 + (d0 - 128) + tcol, (char*)sKl + 4096 + loff);
            }
            __syncthreads();

            bf16x8 a_h[4], a_l[4], b_h[2], b_l[2];
#pragma unroll
            for (int mt = 0; mt < 4; mt++) {
                const int r = (mt * 16 + fr) * 32 + quad * 8;
                a_h[mt] = *(const bf16x8*)&sQh[r];
                a_l[mt] = *(const bf16x8*)&sQl[r];
            }
#pragma unroll
            for (int nt = 0; nt < 2; nt++) {
                const int r = (wn + nt * 16 + fr) * 32 + quad * 8;
                b_h[nt] = *(const bf16x8*)&sKh[r];
                b_l[nt] = *(const bf16x8*)&sKl[r];
            }
#pragma unroll
            for (int mt = 0; mt < 4; mt++)
#pragma unroll
                for (int nt = 0; nt < 2; nt++) {
                    S[mt][nt] = __builtin_amdgcn_mfma_f32_16x16x32_bf16(
                        a_l[mt], b_h[nt], S[mt][nt], 0, 0, 0);
                    S[mt][nt] = __builtin_amdgcn_mfma_f32_16x16x32_bf16(
                        a_h[mt], b_l[nt], S[mt][nt], 0, 0, 0);
                    S[mt][nt] = __builtin_amdgcn_mfma_f32_16x16x32_bf16(
                        a_h[mt], b_h[nt], S[mt][nt], 0, 0, 0);
                }
        }

        // ---- online softmax ----
        float al[16];
#pragma unroll
        for (int mt = 0; mt < 4; mt++)
#pragma unroll
            for (int rr = 0; rr < 4; rr++) {
                const int ri = mt * 16 + quad * 4 + rr;
                const int rowg = q0 + ri;
                float v0 = S[mt][0][rr] * SOFTSCALE;
                float v1 = S[mt][1][rr] * SOFTSCALE;
                if (k0 + wn + fr > rowg)      v0 = -INFINITY;
                if (k0 + wn + 16 + fr > rowg) v1 = -INFINITY;
                S[mt][0][rr] = v0; S[mt][1][rr] = v1;
                float pm = fmaxf(v0, v1);
#pragma unroll
                for (int o = 1; o < 16; o <<= 1) pm = fmaxf(pm, __shfl_xor(pm, o, 64));
                if (fr == 0) redM[ri][wave] = pm;
            }
        __syncthreads();
#pragma unroll
        for (int mt = 0; mt < 4; mt++)
#pragma unroll
            for (int rr = 0; rr < 4; rr++) {
                const int idx = mt * 4 + rr;
                const int ri = mt * 16 + quad * 4 + rr;
                const float4 g = *(const float4*)&redM[ri][0];
                const float gm = fmaxf(fmaxf(g.x, g.y), fmaxf(g.z, g.w));
                const float mn = fmaxf(m_i[idx], gm);
                al[idx] = __expf(m_i[idx] - mn);
                m_i[idx] = mn;
            }
#pragma unroll
        for (int mt = 0; mt < 4; mt++)
#pragma unroll
            for (int rr = 0; rr < 4; rr++) {
                const int idx = mt * 4 + rr;
                const int ri = mt * 16 + quad * 4 + rr;
                const float p0 = __expf(S[mt][0][rr] - m_i[idx]);
                const float p1 = __expf(S[mt][1][rr] - m_i[idx]);
                Ps[ri * 128 + wn + fr]      = __float2bfloat16(p0);
                Ps[ri * 128 + wn + 16 + fr] = __float2bfloat16(p1);
                float ps = p0 + p1;
#pragma unroll
                for (int o = 1; o < 16; o <<= 1) ps += __shfl_xor(ps, o, 64);
                if (fr == 0) redS[ri][wave] = ps;
            }
#pragma unroll
        for (int mt = 0; mt < 4; mt++)
#pragma unroll
            for (int nt = 0; nt < 2; nt++)
#pragma unroll
                for (int rr = 0; rr < 4; rr++) O[mt][nt][rr] *= al[mt * 4 + rr];
        __syncthreads();
#pragma unroll
        for (int mt = 0; mt < 4; mt++)
#pragma unroll
            for (int rr = 0; rr < 4; rr++) {
                const int idx = mt * 4 + rr;
                const int ri = mt * 16 + quad * 4 + rr;
                const float4 s4 = *(const float4*)&redS[ri][0];
                l_i[idx] = l_i[idx] * al[idx] + (s4.x + s4.y + s4.z + s4.w);
            }

        // ---- PV ----
        for (int vch = 0; vch < 4; vch++) {
            if (vch) __syncthreads();
            GLOAD_LDS16(vT + ((size_t)(h * 128 + trow)) * 2048 + k0 + vch * 32 + tcol,      (char*)sVt + loff);
            GLOAD_LDS16(vT + ((size_t)(h * 128 + 64 + trow)) * 2048 + k0 + vch * 32 + tcol, (char*)sVt + 4096 + loff);
            __syncthreads();
            bf16x8 ap[4], bv[2];
#pragma unroll
            for (int mt = 0; mt < 4; mt++)
                ap[mt] = *(const bf16x8*)&Ps[(mt * 16 + fr) * 128 + vch * 32 + quad * 8];
#pragma unroll
            for (int nt = 0; nt < 2; nt++)
                bv[nt] = *(const bf16x8*)&sVt[(wn + nt * 16 + fr) * 32 + quad * 8];
#pragma unroll
            for (int mt = 0; mt < 4; mt++)
#pragma unroll
                for (int nt = 0; nt < 2; nt++)
                    O[mt][nt] = __builtin_amdgcn_mfma_f32_16x16x32_bf16(
                        ap[mt], bv[nt], O[mt][nt], 0, 0, 0);
        }
    }

    // ---- epilogue: y = O / l, split store ----
#pragma unroll
    for (int mt = 0; mt < 4; mt++)
#pragma unroll
        for (int rr = 0; rr < 4; rr++) {
            const float inv = 1.0f / l_i[mt * 4 + rr];
            const int row = q0 + mt * 16 + quad * 4 + rr;
#pragma unroll
            for (int nt = 0; nt < 2; nt++) {
                const int col = wn + nt * 16 + fr;
                const float v = O[mt][nt][rr] * inv;
                bf h8, l8; split2(v, &h8, &l8);
                yh[((size_t)row * 16 + h) * 128 + col] = h8;
                yl[((size_t)row * 16 + h) * 128 + col] = l8;
            }
        }
}

// ---------------------------------------------------------------------------
extern "C" void kernel_launch(void* const* d_in, const int* in_sizes, int n_in,
                              void* d_out, int out_size, void* d_ws, size_t ws_size,
                              hipStream_t stream)
{
    const float* x        = (const float*)d_in[0];
    const float* freqs    = (const float*)d_in[1];
    const float* wq_a     = (const float*)d_in[3];
    const float* q_norm_w = (const float*)d_in[4];
    const float* wq_b     = (const float*)d_in[5];
    const float* wkv_a    = (const float*)d_in[6];
    const float* kv_norm_w= (const float*)d_in[7];
    const float* wkv_b    = (const float*)d_in[8];
    const float* wo       = (const float*)d_in[9];
    float* out            = (float*)d_out;

    char* ws = (char*)d_ws;
    // Region A (0..16.78M): xh/xl, later yh/yl
    bf* xh = (bf*)(ws);
    bf* xl = (bf*)(ws + 8388608);
    bf* yh = (bf*)(ws);
    bf* yl = (bf*)(ws + 8388608);
    // Arena (16.78M..33.55M), time-multiplexed
    char* AR = ws + 16777216;
    bf*    wah    = (bf*)(AR);
    bf*    wal    = (bf*)(AR + 3145728);
    float* qa     = (float*)(AR + 6291456);
    bf*    qah    = (bf*)(AR);
    bf*    qal    = (bf*)(AR + 3145728);
    bf*    wbh    = (bf*)(AR + 6291456);
    bf*    wbl    = (bf*)(AR + 11010048);
    bf*    kah    = (bf*)(AR);
    bf*    kal    = (bf*)(AR + 2359296);
    float* kvfull = (float*)(AR + 4718592);
    bf*    ckvh   = (bf*)(AR + 9437184);
    bf*    ckvl   = (bf*)(AR + 11534336);
    bf*    wvh    = (bf*)(AR);
    bf*    wvl    = (bf*)(AR + 4194304);
    bf*    vT     = (bf*)(AR);
    bf*    woh    = (bf*)(AR);
    bf*    wol    = (bf*)(AR + 8388608);
    // Persistent
    bf* qh   = (bf*)(ws + 33554432);
    bf* ql   = (bf*)(ws + 46137344);
    bf* knh  = (bf*)(ws + 58720256);
    bf* knl  = (bf*)(ws + 67108864);
    bf* vh   = (bf*)(ws + 75497472);
    bf* kpeh = (bf*)(ws + 83886080);
    bf* kpel = (bf*)(ws + 84148224);

    dim3 blk(256);

    // 1) splits
    cvt_split<<<4096, blk, 0, stream>>>(x, xh, xl, D_MODEL * D_MODEL);
    cvt_split<<<1536, blk, 0, stream>>>(wq_a, wah, wal, QLORA * D_MODEL);
    // 2) qa = x @ wq_a^T (fp32 out)
    gemm_split<0><<<dim3(6, 16), blk, 0, stream>>>(
        xh, xl, wah, wal, nullptr, qa, nullptr, nullptr, nullptr,
        T_DIM, QLORA, D_MODEL);
    // 3) rmsnorm + split
    rmsnorm_cvt<<<T_DIM, blk, 0, stream>>>(qa, QLORA, QLORA, q_norm_w, qah, qal);
    // 4) q = qa_norm @ wq_b^T, fused rope + split -> qh/ql
    cvt_split<<<2304, blk, 0, stream>>>(wq_b, wbh, wbl, 3072 * QLORA);
    gemm_split<1><<<dim3(24, 16), blk, 0, stream>>>(
        qah, qal, wbh, wbl, freqs, nullptr, qh, ql, nullptr,
        T_DIM, 3072, QLORA);
    // 5) kvfull = x @ wkv_a^T (fp32 out, N=576 guarded)
    cvt_split<<<1152, blk, 0, stream>>>(wkv_a, kah, kal, KVFULL_D * D_MODEL);
    gemm_split<0><<<dim3(5, 16), blk, 0, stream>>>(
        xh, xl, kah, kal, nullptr, kvfull, nullptr, nullptr, nullptr,
        T_DIM, KVFULL_D, D_MODEL);
    // 6) k_pe rope + split
    rope_k_cvt<<<256, blk, 0, stream>>>(kvfull, freqs, kpeh, kpel);
    // 7) c_kv rmsnorm + split
    rmsnorm_cvt<<<T_DIM, blk, 0, stream>>>(kvfull, KVFULL_D, KVLORA, kv_norm_w, ckvh, ckvl);
    // 8) kv = ckv @ wkv_b^T, fused split -> knh/knl + vh
    cvt_split<<<2048, blk, 0, stream>>>(wkv_b, wvh, wvl, 4096 * KVLORA);
    gemm_split<2><<<dim3(32, 16), blk, 0, stream>>>(
        ckvh, ckvl, wvh, wvl, nullptr, nullptr, knh, knl, vh,
        T_DIM, 4096, KVLORA);
    // 9) transpose v -> vT (H,128,T)
    transpose_v<<<dim3(64, 4, 16), blk, 0, stream>>>(vh, vT);
    // 10) attention -> yh/yl
    attn_mfma<<<dim3(512), blk, 0, stream>>>(
        qh, ql, knh, knl, kpeh, kpel, vT, yh, yl);
    // 11) out = y @ wo^T (fp32 out)
    cvt_split<<<4096, blk, 0, stream>>>(wo, woh, wol, D_MODEL * D_MODEL);
    gemm_split<0><<<dim3(16, 16), blk, 0, stream>>>(
        yh, yl, woh, wol, nullptr, out, nullptr, nullptr, nullptr,
        T_DIM, D_MODEL, D_MODEL);
}